// Round 3
// baseline (667.974 us; speedup 1.0000x reference)
//
#include <hip/hip_runtime.h>

// ---------------------------------------------------------------------------
// InvariantPolynomial, round 5: k_mid occupancy + edge-parallel + wide gathers.
//
// Round-4 result: k_out fixed (occupancy), k_mid now dominant (183us):
// Occupancy 21.7%, VALUBusy 17%, HBM 2.4% -> latency-bound, plus 2/3 lanes
// idle (48-slot stride vs avg degree 16).
//
// This round:
//  * csr packs block-local dst index: s | (q<<16) | ((d&15)<<20).
//  * k_mid: 1024 thr / 16 nodes / block; LDS = lw 27.6KB + G 52.2KB = 79.9KB
//    -> 2 blocks/CU = 100% occupancy; phase 1 fully edge-parallel.
//  * pos packed to float4 (pos4), node_sh padded to stride 12 -> per-edge
//    VMEM instrs 13 -> 5.
//
// ws layout (ints/floats):
//   counts  @ int   [0      , 20000)
//   start   @ int   [32768  , 52769)
//   cursor  @ int   [65536  , 85536)
//   csr     @ int   [98304  , 418304)
//   pos4    @ float [425984 , 505984)     20000 x 4
//   node_sh @ float [524288 , 764288)     20000 x 12 (9 used, inv_nn folded)
//   mid     @ float [1048576, 8408576)    20000 x 368
// ---------------------------------------------------------------------------

#define N_EDGES   320000
#define NN_NODES  20000
#define NN_GRAPHS 5000

__device__ __forceinline__ void sh_from_vec(float x, float y, float z,
                                            float* B1, float* B2) {
    const float s3   = 1.7320508075688772f;
    const float s15  = 3.8729833462074170f;
    const float s5h  = 1.1180339887498949f;
    const float s15h = 1.9364916731037085f;
    B1[0] = s3 * y; B1[1] = s3 * z; B1[2] = s3 * x;
    float r2 = x * x + y * y + z * z;
    B2[0] = s15 * x * y;
    B2[1] = s15 * y * z;
    B2[2] = s5h * (3.f * z * z - r2);
    B2[3] = s15 * x * z;
    B2[4] = s15h * (x * x - y * y);
}

// --------------------------- zero + pos4 pack ------------------------------
__global__ __launch_bounds__(256) void k_zero(const float* __restrict__ pos,
                                              int* __restrict__ counts,
                                              float* __restrict__ out,
                                              float4* __restrict__ pos4) {
    int tid = blockIdx.x * blockDim.x + threadIdx.x;
    int stride = gridDim.x * blockDim.x;
    for (int i = tid; i < NN_NODES; i += stride) counts[i] = 0;
    for (int i = tid; i < NN_GRAPHS * 7; i += stride) out[i] = 0.f;
    for (int i = tid; i < NN_NODES; i += stride) {
        float4 p;
        p.x = pos[3 * i]; p.y = pos[3 * i + 1]; p.z = pos[3 * i + 2]; p.w = 0.f;
        pos4[i] = p;
    }
}

// --------------------------- histogram -------------------------------------
__global__ __launch_bounds__(256) void k_hist(const int* __restrict__ edst,
                                              int* __restrict__ counts) {
    int e = blockIdx.x * blockDim.x + threadIdx.x;
    if (e < N_EDGES) atomicAdd(&counts[edst[e]], 1);
}

// --------------------------- exclusive scan (1 block of 1024) --------------
__global__ __launch_bounds__(1024) void k_scan(const int* __restrict__ counts,
                                               int* __restrict__ start,
                                               int* __restrict__ cursor) {
    __shared__ int sdata[1024];
    __shared__ int carry;
    int tid = threadIdx.x;
    if (tid == 0) carry = 0;
    __syncthreads();
    for (int base = 0; base < NN_NODES; base += 1024) {
        int i = base + tid;
        int v = (i < NN_NODES) ? counts[i] : 0;
        sdata[tid] = v;
        __syncthreads();
        for (int off = 1; off < 1024; off <<= 1) {
            int t = (tid >= off) ? sdata[tid - off] : 0;
            __syncthreads();
            sdata[tid] += t;
            __syncthreads();
        }
        int incl = sdata[tid];
        int c = carry;
        if (i < NN_NODES) {
            int excl = c + incl - v;
            start[i] = excl;
            cursor[i] = excl;
        }
        __syncthreads();
        if (tid == 0) carry = c + sdata[1023];
        __syncthreads();
    }
    if (tid == 0) start[NN_NODES] = carry;   // = N_EDGES
}

// --------------------------- CSR fill --------------------------------------
__global__ __launch_bounds__(256) void k_fill(const int* __restrict__ esrc,
                                              const int* __restrict__ edst,
                                              const int* __restrict__ zarr,
                                              int* __restrict__ cursor,
                                              int* __restrict__ csr) {
    int e = blockIdx.x * blockDim.x + threadIdx.x;
    if (e >= N_EDGES) return;
    int d = edst[e];
    int s = esrc[e];
    int q = 4 * zarr[s] + zarr[d];
    int p = atomicAdd(&cursor[d], 1);
    csr[p] = s | (q << 16) | ((d & 15) << 20);
}

// --------------------------- node_sh gather (wave per node) ----------------
__global__ __launch_bounds__(256) void k_nodesh(const float4* __restrict__ pos4,
                                                const int* __restrict__ start,
                                                const int* __restrict__ csr,
                                                float* __restrict__ node_sh) {
    int wave = threadIdx.x >> 6;
    int lane = threadIdx.x & 63;
    int n = blockIdx.x * 4 + wave;
    if (n >= NN_NODES) return;
    float4 pd = pos4[n];
    int s0 = start[n], s1 = start[n + 1];
    float acc[9] = {0.f, 0.f, 0.f, 0.f, 0.f, 0.f, 0.f, 0.f, 0.f};
    for (int idx = s0 + lane; idx < s1; idx += 64) {
        int s = csr[idx] & 0xFFFF;
        float4 ps = pos4[s];
        float x = ps.x - pd.x;
        float y = ps.y - pd.y;
        float z = ps.z - pd.z;
        float B1[3], B2[5];
        sh_from_vec(x, y, z, B1, B2);
        acc[0] += 1.f;
        acc[1] += B1[0]; acc[2] += B1[1]; acc[3] += B1[2];
        acc[4] += B2[0]; acc[5] += B2[1]; acc[6] += B2[2];
        acc[7] += B2[3]; acc[8] += B2[4];
    }
#pragma unroll
    for (int off = 32; off > 0; off >>= 1)
#pragma unroll
        for (int i = 0; i < 9; i++) acc[i] += __shfl_down(acc[i], off, 64);
    if (lane == 0) {
        const float inv_nn = 0.57735026918962576f;
#pragma unroll
        for (int i = 0; i < 9; i++) node_sh[n * 12 + i] = acc[i] * inv_nn;
    }
}

// --------------- fused TP1: G in LDS -> W1 contraction -> mid --------------
// 1024 threads, 16 nodes/block, fully edge-parallel phase 1.
// LDS: lw 6912 + Gl 13056 floats = 79872 B -> 2 blocks/CU (100% occupancy).
__global__ __launch_bounds__(1024, 8) void k_mid(const float4* __restrict__ pos4,
                                                 const float* __restrict__ node_sh,
                                                 const int* __restrict__ start,
                                                 const int* __restrict__ csr,
                                                 const float* __restrict__ w1,
                                                 float* __restrict__ mid) {
    __shared__ float lw[6912];
    __shared__ float Gl[16 * 816];
    int t = threadIdx.x;
    for (int i = t; i < 6912; i += 1024) lw[i] = w1[i];
    for (int i = t; i < 16 * 816; i += 1024) Gl[i] = 0.f;
    __syncthreads();

    int nbase = blockIdx.x * 16;
    int e0 = start[nbase], e1 = start[nbase + 16];

    const float r3  = 0.57735026918962576f;
    const float r5  = 0.44721359549995794f;
    const float r6  = 0.40824829046386302f;
    const float r10 = 0.31622776601683794f;
    const float s30 = 0.18257418583505536f;
    const float rt3 = 1.7320508075688772f;
    const float c222 = 0.58554004376911990f;
    const float q6 = 0.40824829046386302f;
    const float h6 = 0.20412414523193151f;
    const float h2 = 0.35355339059327376f;
    const float r2c = 0.70710678118654752f;

    for (int idx = e0 + t; idx < e1; idx += 1024) {
        int pk = csr[idx];
        int s = pk & 0xFFFF;
        int q = (pk >> 16) & 15;
        int r = (pk >> 20) & 15;
        float4 pd = pos4[nbase + r];
        float4 ps = pos4[s];
        float x = ps.x - pd.x;
        float y = ps.y - pd.y;
        float z = ps.z - pd.z;
        float B1[3], B2[5];
        sh_from_vec(x, y, z, B1, B2);
        const float4 nv0 = *(const float4*)(node_sh + s * 12);
        const float4 nv1 = *(const float4*)(node_sh + s * 12 + 4);
        float a0 = nv0.x;
        float A1[3] = {nv0.y, nv0.z, nv0.w};
        float A2[5] = {nv1.x, nv1.y, nv1.z, nv1.w, node_sh[s * 12 + 8]};
        float* gr = Gl + r * 816 + q * 51;

        atomicAdd(gr + 0, a0);
        atomicAdd(gr + 1, a0 * B1[0] * r3);
        atomicAdd(gr + 2, a0 * B1[1] * r3);
        atomicAdd(gr + 3, a0 * B1[2] * r3);
        atomicAdd(gr + 4, a0 * B2[0] * r5);
        atomicAdd(gr + 5, a0 * B2[1] * r5);
        atomicAdd(gr + 6, a0 * B2[2] * r5);
        atomicAdd(gr + 7, a0 * B2[3] * r5);
        atomicAdd(gr + 8, a0 * B2[4] * r5);
        atomicAdd(gr + 9,  A1[0] * r3);
        atomicAdd(gr + 10, A1[1] * r3);
        atomicAdd(gr + 11, A1[2] * r3);
        atomicAdd(gr + 12, -r3 * (A1[0] * B1[0] + A1[1] * B1[1] + A1[2] * B1[2]));
        atomicAdd(gr + 13, -r6 * (A1[1] * B1[2] - A1[2] * B1[1]));
        atomicAdd(gr + 14, -r6 * (A1[2] * B1[0] - A1[0] * B1[2]));
        atomicAdd(gr + 15, -r6 * (A1[0] * B1[1] - A1[1] * B1[0]));
        atomicAdd(gr + 16, r10 * (A1[0] * B1[2] + A1[2] * B1[0]));
        atomicAdd(gr + 17, r10 * (A1[0] * B1[1] + A1[1] * B1[0]));
        atomicAdd(gr + 18, s30 * (2.f * A1[1] * B1[1] - A1[0] * B1[0] - A1[2] * B1[2]));
        atomicAdd(gr + 19, r10 * (A1[1] * B1[2] + A1[2] * B1[1]));
        atomicAdd(gr + 20, r10 * (A1[2] * B1[2] - A1[0] * B1[0]));
        {
            float Byy = -B2[2] * q6 - B2[4] * r2c;
            float Bzz = 2.f * B2[2] * q6;
            float Bxx = -B2[2] * q6 + B2[4] * r2c;
            float Bxy = B2[0] * r2c;
            float Byz = B2[1] * r2c;
            float Bxz = B2[3] * r2c;
            atomicAdd(gr + 21, -r5 * (Byy * A1[0] + Byz * A1[1] + Bxy * A1[2]));
            atomicAdd(gr + 22, -r5 * (Byz * A1[0] + Bzz * A1[1] + Bxz * A1[2]));
            atomicAdd(gr + 23, -r5 * (Bxy * A1[0] + Bxz * A1[1] + Bxx * A1[2]));
        }
        atomicAdd(gr + 24, -s30 * (B2[1] * A1[0] - B2[3] * A1[2] + 2.f * B2[4] * A1[1]));
        atomicAdd(gr + 25, -s30 * (-B2[0] * A1[0] - rt3 * B2[2] * A1[2] + B2[3] * A1[1] - B2[4] * A1[2]));
        atomicAdd(gr + 26, -s30 * (rt3 * B2[1] * A1[2] - rt3 * B2[3] * A1[0]));
        atomicAdd(gr + 27, -s30 * (B2[0] * A1[2] - B2[1] * A1[1] + rt3 * B2[2] * A1[0] - B2[4] * A1[0]));
        atomicAdd(gr + 28, -s30 * (-2.f * B2[0] * A1[1] + B2[1] * A1[2] + B2[3] * A1[0]));
        atomicAdd(gr + 29, A2[0] * r5);
        atomicAdd(gr + 30, A2[1] * r5);
        atomicAdd(gr + 31, A2[2] * r5);
        atomicAdd(gr + 32, A2[3] * r5);
        atomicAdd(gr + 33, A2[4] * r5);
        {
            float Ayy = -A2[2] * q6 - A2[4] * r2c;
            float Azz = 2.f * A2[2] * q6;
            float Axx = -A2[2] * q6 + A2[4] * r2c;
            float Axy = A2[0] * r2c;
            float Ayz = A2[1] * r2c;
            float Axz = A2[3] * r2c;
            atomicAdd(gr + 34, -r5 * (Ayy * B1[0] + Ayz * B1[1] + Axy * B1[2]));
            atomicAdd(gr + 35, -r5 * (Ayz * B1[0] + Azz * B1[1] + Axz * B1[2]));
            atomicAdd(gr + 36, -r5 * (Axy * B1[0] + Axz * B1[1] + Axx * B1[2]));
        }
        atomicAdd(gr + 37, s30 * (A2[1] * B1[0] - A2[3] * B1[2] + 2.f * A2[4] * B1[1]));
        atomicAdd(gr + 38, s30 * (-A2[0] * B1[0] - rt3 * A2[2] * B1[2] + A2[3] * B1[1] - A2[4] * B1[2]));
        atomicAdd(gr + 39, s30 * (rt3 * A2[1] * B1[2] - rt3 * A2[3] * B1[0]));
        atomicAdd(gr + 40, s30 * (A2[0] * B1[2] - A2[1] * B1[1] + rt3 * A2[2] * B1[0] - A2[4] * B1[0]));
        atomicAdd(gr + 41, s30 * (-2.f * A2[0] * B1[1] + A2[1] * B1[2] + A2[3] * B1[0]));
        atomicAdd(gr + 42, r5 * (A2[0] * B2[0] + A2[1] * B2[1] + A2[2] * B2[2] +
                                 A2[3] * B2[3] + A2[4] * B2[4]));
        atomicAdd(gr + 43, s30 * (-A2[0] * B2[1] + A2[1] * B2[0] +
                                  rt3 * (A2[2] * B2[3] - A2[3] * B2[2]) +
                                  A2[3] * B2[4] - A2[4] * B2[3]));
        atomicAdd(gr + 44, s30 * (-2.f * A2[0] * B2[4] + 2.f * A2[4] * B2[0] -
                                  A2[1] * B2[3] + A2[3] * B2[1]));
        atomicAdd(gr + 45, s30 * (A2[0] * B2[3] - A2[3] * B2[0] +
                                  rt3 * (A2[1] * B2[2] - A2[2] * B2[1]) +
                                  A2[1] * B2[4] - A2[4] * B2[1]));
        atomicAdd(gr + 46, -c222 * (-q6 * (A2[0] * B2[2] + A2[2] * B2[0]) +
                                    h2 * (A2[1] * B2[3] + A2[3] * B2[1])));
        atomicAdd(gr + 47, -c222 * (h6 * (A2[1] * B2[2] + A2[2] * B2[1]) -
                                    h2 * (A2[1] * B2[4] + A2[4] * B2[1]) +
                                    h2 * (A2[0] * B2[3] + A2[3] * B2[0])));
        atomicAdd(gr + 48, -c222 * (q6 * (A2[2] * B2[2] - A2[0] * B2[0] - A2[4] * B2[4]) +
                                    h6 * (A2[1] * B2[1] + A2[3] * B2[3])));
        atomicAdd(gr + 49, -c222 * (h6 * (A2[3] * B2[2] + A2[2] * B2[3]) +
                                    h2 * (A2[3] * B2[4] + A2[4] * B2[3]) +
                                    h2 * (A2[0] * B2[1] + A2[1] * B2[0])));
        atomicAdd(gr + 50, -c222 * (-q6 * (A2[4] * B2[2] + A2[2] * B2[4]) +
                                    h2 * (A2[3] * B2[3] - A2[1] * B2[1])));
    }
    __syncthreads();

    // Phase 2: threads 0..735 cover (chunk of 8 nodes) x (368 outputs).
    if (t >= 736) return;
    int chunk = t / 368;            // 0 or 1
    int j = t - 368 * chunk;        // 0..367
    int rb = chunk * 8;
    if (j < 64) {
        int w = j;
        for (int r2 = rb; r2 < rb + 8; r2++) {
            const float* Gn = Gl + r2 * 816;
            float acc = 0.f;
            for (int q = 0; q < 16; q++) {
                const float* gq = Gn + q * 51;
                acc += gq[0]  * lw[q * 64 + w]
                     + gq[12] * lw[2048 + q * 64 + w]
                     + gq[42] * lw[5248 + q * 64 + w];
            }
            mid[(size_t)(nbase + r2) * 368 + j] = 0.33333333333333333f * acc;
        }
    } else if (j < 136) {
        int tt = j - 64, w = tt / 3, k = tt - 3 * w;
        for (int r2 = rb; r2 < rb + 8; r2++) {
            const float* Gn = Gl + r2 * 816;
            float acc = 0.f;
            for (int q = 0; q < 16; q++) {
                const float* gq = Gn + q * 51;
                acc += gq[13 + k] * lw[3072 + q * 24 + w]
                     + gq[43 + k] * lw[6272 + q * 24 + w];
            }
            mid[(size_t)(nbase + r2) * 368 + j] = 0.70710678118654752f * acc;
        }
    } else if (j < 208) {
        int tt = j - 136, w = tt / 3, k = tt - 3 * w;
        for (int r2 = rb; r2 < rb + 8; r2++) {
            const float* Gn = Gl + r2 * 816;
            float acc = 0.f;
            for (int q = 0; q < 16; q++) {
                const float* gq = Gn + q * 51;
                acc += gq[1 + k]  * lw[1024 + q * 24 + w]
                     + gq[9 + k]  * lw[1664 + q * 24 + w]
                     + gq[21 + k] * lw[3712 + q * 24 + w]
                     + gq[34 + k] * lw[4608 + q * 24 + w];
            }
            mid[(size_t)(nbase + r2) * 368 + j] = 0.5f * acc;
        }
    } else if (j < 288) {
        int tt = j - 208, w = tt / 5, k = tt - 5 * w;
        for (int r2 = rb; r2 < rb + 8; r2++) {
            const float* Gn = Gl + r2 * 816;
            float acc = 0.f;
            for (int q = 0; q < 16; q++) {
                const float* gq = Gn + q * 51;
                acc += gq[4 + k]  * lw[1408 + q * 16 + w]
                     + gq[16 + k] * lw[3456 + q * 16 + w]
                     + gq[29 + k] * lw[4352 + q * 16 + w]
                     + gq[46 + k] * lw[6656 + q * 16 + w];
            }
            mid[(size_t)(nbase + r2) * 368 + j] = 0.64549722436790280f * acc;
        }
    } else {
        int tt = j - 288, w = tt / 5, k = tt - 5 * w;
        for (int r2 = rb; r2 < rb + 8; r2++) {
            const float* Gn = Gl + r2 * 816;
            float acc = 0.f;
            for (int q = 0; q < 16; q++) {
                const float* gq = Gn + q * 51;
                acc += gq[24 + k] * lw[4096 + q * 16 + w]
                     + gq[37 + k] * lw[4992 + q * 16 + w];
            }
            mid[(size_t)(nbase + r2) * 368 + j] = 0.91287092917527690f * acc;
        }
    }
}

// --------------- fused TP2 + graph reduce (wave per node) ------------------
// 1024 threads = 16 waves = 16 nodes/block; 2 blocks/CU -> 100% occupancy.
__global__ __launch_bounds__(1024, 8) void k_out(const float4* __restrict__ pos4,
                                                 const int* __restrict__ batch,
                                                 const int* __restrict__ start,
                                                 const int* __restrict__ csr,
                                                 const float* __restrict__ mid,
                                                 const float* __restrict__ w2,
                                                 float* __restrict__ out) {
    __shared__ float lw2[10624];
    // Permuted load: dst index -> src index in original [u][q][w] layout.
    for (int i = threadIdx.x; i < 10624; i += 1024) {
        int src;
        if (i < 4096) {                     // R0a: ((q*64+u)*4+w)
            int w = i & 3, u = (i >> 2) & 63, q = i >> 8;
            src = (u * 16 + q) * 6 + w;
        } else if (i < 6144) {              // R0b
            int t2 = i - 4096;
            int w = t2 & 1, u = (t2 >> 1) & 63, q = t2 >> 7;
            src = (u * 16 + q) * 6 + 4 + w;
        } else if (i < 6528) {              // R1: q*24+u
            int t2 = i - 6144;
            int u = t2 % 24, q = t2 / 24;
            src = 6144 + u * 16 + q;
        } else if (i < 8064) {              // R2a
            int t2 = i - 6528;
            int w = t2 & 3, a = t2 >> 2;
            int u = a % 24, q = a / 24;
            src = 6528 + (u * 16 + q) * 6 + w;
        } else if (i < 8832) {              // R2b
            int t2 = i - 8064;
            int w = t2 & 1, a = t2 >> 1;
            int u = a % 24, q = a / 24;
            src = 6528 + (u * 16 + q) * 6 + 4 + w;
        } else if (i < 9856) {              // R3a
            int t2 = i - 8832;
            int w = t2 & 3, a = t2 >> 2;
            int u = a & 15, q = a >> 4;
            src = 8832 + (u * 16 + q) * 6 + w;
        } else if (i < 10368) {             // R3b
            int t2 = i - 9856;
            int w = t2 & 1, a = t2 >> 1;
            int u = a & 15, q = a >> 4;
            src = 8832 + (u * 16 + q) * 6 + 4 + w;
        } else {                            // R4: q*16+u
            int t2 = i - 10368;
            int u = t2 & 15, q = t2 >> 4;
            src = 10368 + u * 16 + q;
        }
        lw2[i] = w2[src];
    }
    __syncthreads();

    int wave = threadIdx.x >> 6;
    int lane = threadIdx.x & 63;
    int n = blockIdx.x * 16 + wave;     // grid = 1250 -> n < 20000 always
    float4 pd = pos4[n];
    int s0 = start[n], s1 = start[n + 1];

    // per-lane unified mid-row offset for the T1/T2/T3 slot
    int offA;
    if (lane < 24)      offA = 64  + 3 * lane;            // T1, dot3
    else if (lane < 48) offA = 136 + 3 * (lane - 24);     // T2, dot3
    else                offA = 208 + 5 * (lane - 48);     // T3, dot5
    const int offB = 288 + 5 * lane;                      // T4 (lanes<16), dot5

    // per-lane u-slot partials
    float p0[6] = {0.f, 0.f, 0.f, 0.f, 0.f, 0.f};   // T0, u = lane
    float pA[6] = {0.f, 0.f, 0.f, 0.f, 0.f, 0.f};   // T1/T2/T3 by lane range
    float pB = 0.f;                                  // T4, lanes 0..15

    for (int idx = s0; idx < s1; ++idx) {
        int pk = csr[idx];
        pk = __builtin_amdgcn_readfirstlane(pk);     // wave-uniform -> scalar
        int s = pk & 0xFFFF;
        int q = (pk >> 16) & 15;
        const float* mrow = mid + (size_t)s * 368;

        // ---- issue all gathers up front ----
        float m  = mrow[lane];
        float a0 = mrow[offA], a1 = mrow[offA + 1], a2 = mrow[offA + 2];
        float a3 = 0.f, a4 = 0.f;
        if (lane >= 48) { a3 = mrow[offA + 3]; a4 = mrow[offA + 4]; }
        float b0 = 0.f, b1 = 0.f, b2 = 0.f, b3 = 0.f, b4 = 0.f;
        if (lane < 16) {
            b0 = mrow[offB];     b1 = mrow[offB + 1]; b2 = mrow[offB + 2];
            b3 = mrow[offB + 3]; b4 = mrow[offB + 4];
        }
        float4 ps = pos4[s];
        float x = ps.x - pd.x;
        float y = ps.y - pd.y;
        float z = ps.z - pd.z;

        float B1[3], B2[5];
        sh_from_vec(x, y, z, B1, B2);

        // T0: u = lane; weights 1x b128 + 1x b64, lanes contiguous
        {
            const float4 wv  = *(const float4*)(lw2 + q * 256 + lane * 4);
            const float2 wv2 = *(const float2*)(lw2 + 4096 + q * 128 + lane * 2);
            p0[0] += m * wv.x;  p0[1] += m * wv.y;
            p0[2] += m * wv.z;  p0[3] += m * wv.w;
            p0[4] += m * wv2.x; p0[5] += m * wv2.y;
        }
        // unified dd for the slot
        float dd;
        if (lane < 48) dd = a0 * B1[0] + a1 * B1[1] + a2 * B1[2];
        else           dd = a0 * B2[0] + a1 * B2[1] + a2 * B2[2] +
                            a3 * B2[3] + a4 * B2[4];
        // weight application
        if (lane < 24) {            // T1
            pA[0] += dd * lw2[6144 + q * 24 + lane];
        } else if (lane < 48) {     // T2
            int u = lane - 24;
            const float4 wv  = *(const float4*)(lw2 + 6528 + q * 96 + u * 4);
            const float2 wv2 = *(const float2*)(lw2 + 8064 + q * 48 + u * 2);
            pA[0] += dd * wv.x;  pA[1] += dd * wv.y;
            pA[2] += dd * wv.z;  pA[3] += dd * wv.w;
            pA[4] += dd * wv2.x; pA[5] += dd * wv2.y;
        } else {                    // T3
            int u = lane - 48;
            const float4 wv  = *(const float4*)(lw2 + 8832 + q * 64 + u * 4);
            const float2 wv2 = *(const float2*)(lw2 + 9856 + q * 32 + u * 2);
            pA[0] += dd * wv.x;  pA[1] += dd * wv.y;
            pA[2] += dd * wv.z;  pA[3] += dd * wv.w;
            pA[4] += dd * wv2.x; pA[5] += dd * wv2.y;
        }
        // T4: lanes 0..15
        if (lane < 16) {
            float ddB = b0 * B2[0] + b1 * B2[1] + b2 * B2[2] +
                        b3 * B2[3] + b4 * B2[4];
            pB += ddB * lw2[10368 + q * 16 + lane];
        }
    }

    const float cT0f =  0.02830690f;
    const float cT1f = -0.02635231f;
    const float cT2f = -0.01634300f;
    const float cT3f =  0.01265893f;
    const float cT4f =  0.02041241f;

    float o0 = 0.f;
    float ov[6];
#pragma unroll
    for (int w = 0; w < 6; w++) ov[w] = cT0f * p0[w];
    if (lane < 24) {
        o0 += cT1f * pA[0];
    } else if (lane < 48) {
#pragma unroll
        for (int w = 0; w < 6; w++) ov[w] += cT2f * pA[w];
    } else {
#pragma unroll
        for (int w = 0; w < 6; w++) ov[w] += cT3f * pA[w];
    }
    if (lane < 16) o0 += cT4f * pB;

#pragma unroll
    for (int off = 32; off > 0; off >>= 1) {
        o0 += __shfl_down(o0, off, 64);
#pragma unroll
        for (int w = 0; w < 6; w++) ov[w] += __shfl_down(ov[w], off, 64);
    }
    if (lane == 0) {
        float* og = out + batch[n] * 7;
        atomicAdd(og + 0, o0);
#pragma unroll
        for (int w = 0; w < 6; w++) atomicAdd(og + 1 + w, ov[w]);
    }
}

// ---------------------------------------------------------------------------
extern "C" void kernel_launch(void* const* d_in, const int* in_sizes, int n_in,
                              void* d_out, int out_size, void* d_ws, size_t ws_size,
                              hipStream_t stream) {
    const float* pos  = (const float*)d_in[0];
    const int*   z    = (const int*)d_in[1];
    const int*   bat  = (const int*)d_in[2];
    const int*   esrc = (const int*)d_in[3];
    const int*   edst = (const int*)d_in[4];
    const float* w1   = (const float*)d_in[5];
    const float* w2   = (const float*)d_in[6];
    float* out = (float*)d_out;

    int*   wsI = (int*)d_ws;
    float* wsF = (float*)d_ws;
    int* counts = wsI + 0;
    int* start  = wsI + 32768;
    int* cursor = wsI + 65536;
    int* csr    = wsI + 98304;
    float4* pos4   = (float4*)(wsF + 425984);
    float* node_sh = wsF + 524288;
    float* mid     = wsF + 1048576;

    k_zero<<<64, 256, 0, stream>>>(pos, counts, out, pos4);
    k_hist<<<(N_EDGES + 255) / 256, 256, 0, stream>>>(edst, counts);
    k_scan<<<1, 1024, 0, stream>>>(counts, start, cursor);
    k_fill<<<(N_EDGES + 255) / 256, 256, 0, stream>>>(esrc, edst, z, cursor, csr);
    k_nodesh<<<NN_NODES / 4, 256, 0, stream>>>(pos4, start, csr, node_sh);
    k_mid<<<NN_NODES / 16, 1024, 0, stream>>>(pos4, node_sh, start, csr, w1, mid);
    k_out<<<NN_NODES / 16, 1024, 0, stream>>>(pos4, bat, start, csr, mid, w2, out);
}

// Round 4
// 415.872 us; speedup vs baseline: 1.6062x; 1.6062x over previous
//
#include <hip/hip_runtime.h>

// ---------------------------------------------------------------------------
// InvariantPolynomial, round 6: un-spill k_mid, keep edge-parallel structure.
//
// Round-5 post-mortem: __launch_bounds__(1024,8) capped VGPR at 64 < the ~72
// the 51-atomic body needs -> scratch spill (WRITE_SIZE 29MB->342MB, VGPR=32,
// 405us). Fix: 512thr/8nodes, __launch_bounds__(512,6) (cap 85 > 72); drop lw
// from LDS (phase 2 reads w1 from global, q-outer with acc[8]) -> LDS 26.1KB
// -> 3 blocks/CU = 24 waves = 75% occupancy, no spill.
//
// ws layout (ints/floats):
//   counts  @ int   [0      , 20000)
//   start   @ int   [32768  , 52769)
//   cursor  @ int   [65536  , 85536)
//   csr     @ int   [98304  , 418304)
//   pos4    @ float [425984 , 505984)     20000 x 4
//   node_sh @ float [524288 , 764288)     20000 x 12 (9 used, inv_nn folded)
//   mid     @ float [1048576, 8408576)    20000 x 368
// ---------------------------------------------------------------------------

#define N_EDGES   320000
#define NN_NODES  20000
#define NN_GRAPHS 5000

__device__ __forceinline__ void sh_from_vec(float x, float y, float z,
                                            float* B1, float* B2) {
    const float s3   = 1.7320508075688772f;
    const float s15  = 3.8729833462074170f;
    const float s5h  = 1.1180339887498949f;
    const float s15h = 1.9364916731037085f;
    B1[0] = s3 * y; B1[1] = s3 * z; B1[2] = s3 * x;
    float r2 = x * x + y * y + z * z;
    B2[0] = s15 * x * y;
    B2[1] = s15 * y * z;
    B2[2] = s5h * (3.f * z * z - r2);
    B2[3] = s15 * x * z;
    B2[4] = s15h * (x * x - y * y);
}

// --------------------------- zero + pos4 pack ------------------------------
__global__ __launch_bounds__(256) void k_zero(const float* __restrict__ pos,
                                              int* __restrict__ counts,
                                              float* __restrict__ out,
                                              float4* __restrict__ pos4) {
    int tid = blockIdx.x * blockDim.x + threadIdx.x;
    int stride = gridDim.x * blockDim.x;
    for (int i = tid; i < NN_NODES; i += stride) counts[i] = 0;
    for (int i = tid; i < NN_GRAPHS * 7; i += stride) out[i] = 0.f;
    for (int i = tid; i < NN_NODES; i += stride) {
        float4 p;
        p.x = pos[3 * i]; p.y = pos[3 * i + 1]; p.z = pos[3 * i + 2]; p.w = 0.f;
        pos4[i] = p;
    }
}

// --------------------------- histogram -------------------------------------
__global__ __launch_bounds__(256) void k_hist(const int* __restrict__ edst,
                                              int* __restrict__ counts) {
    int e = blockIdx.x * blockDim.x + threadIdx.x;
    if (e < N_EDGES) atomicAdd(&counts[edst[e]], 1);
}

// --------------------------- exclusive scan (1 block of 1024) --------------
__global__ __launch_bounds__(1024) void k_scan(const int* __restrict__ counts,
                                               int* __restrict__ start,
                                               int* __restrict__ cursor) {
    __shared__ int sdata[1024];
    __shared__ int carry;
    int tid = threadIdx.x;
    if (tid == 0) carry = 0;
    __syncthreads();
    for (int base = 0; base < NN_NODES; base += 1024) {
        int i = base + tid;
        int v = (i < NN_NODES) ? counts[i] : 0;
        sdata[tid] = v;
        __syncthreads();
        for (int off = 1; off < 1024; off <<= 1) {
            int t = (tid >= off) ? sdata[tid - off] : 0;
            __syncthreads();
            sdata[tid] += t;
            __syncthreads();
        }
        int incl = sdata[tid];
        int c = carry;
        if (i < NN_NODES) {
            int excl = c + incl - v;
            start[i] = excl;
            cursor[i] = excl;
        }
        __syncthreads();
        if (tid == 0) carry = c + sdata[1023];
        __syncthreads();
    }
    if (tid == 0) start[NN_NODES] = carry;   // = N_EDGES
}

// --------------------------- CSR fill --------------------------------------
__global__ __launch_bounds__(256) void k_fill(const int* __restrict__ esrc,
                                              const int* __restrict__ edst,
                                              const int* __restrict__ zarr,
                                              int* __restrict__ cursor,
                                              int* __restrict__ csr) {
    int e = blockIdx.x * blockDim.x + threadIdx.x;
    if (e >= N_EDGES) return;
    int d = edst[e];
    int s = esrc[e];
    int q = 4 * zarr[s] + zarr[d];
    int p = atomicAdd(&cursor[d], 1);
    csr[p] = s | (q << 16) | ((d & 7) << 20);
}

// --------------------------- node_sh gather (wave per node) ----------------
__global__ __launch_bounds__(256) void k_nodesh(const float4* __restrict__ pos4,
                                                const int* __restrict__ start,
                                                const int* __restrict__ csr,
                                                float* __restrict__ node_sh) {
    int wave = threadIdx.x >> 6;
    int lane = threadIdx.x & 63;
    int n = blockIdx.x * 4 + wave;
    if (n >= NN_NODES) return;
    float4 pd = pos4[n];
    int s0 = start[n], s1 = start[n + 1];
    float acc[9] = {0.f, 0.f, 0.f, 0.f, 0.f, 0.f, 0.f, 0.f, 0.f};
    for (int idx = s0 + lane; idx < s1; idx += 64) {
        int s = csr[idx] & 0xFFFF;
        float4 ps = pos4[s];
        float x = ps.x - pd.x;
        float y = ps.y - pd.y;
        float z = ps.z - pd.z;
        float B1[3], B2[5];
        sh_from_vec(x, y, z, B1, B2);
        acc[0] += 1.f;
        acc[1] += B1[0]; acc[2] += B1[1]; acc[3] += B1[2];
        acc[4] += B2[0]; acc[5] += B2[1]; acc[6] += B2[2];
        acc[7] += B2[3]; acc[8] += B2[4];
    }
#pragma unroll
    for (int off = 32; off > 0; off >>= 1)
#pragma unroll
        for (int i = 0; i < 9; i++) acc[i] += __shfl_down(acc[i], off, 64);
    if (lane == 0) {
        const float inv_nn = 0.57735026918962576f;
#pragma unroll
        for (int i = 0; i < 9; i++) node_sh[n * 12 + i] = acc[i] * inv_nn;
    }
}

// --------------- fused TP1: G in LDS -> W1 contraction -> mid --------------
// 512 threads, 8 nodes/block, edge-parallel phase 1.
// LDS: Gl only (6528 floats = 26.1 KB) -> 3 blocks/CU, 24 waves = 75% occ.
// __launch_bounds__(512,6): VGPR cap 85 > ~72 needed -> no spill.
__global__ __launch_bounds__(512, 6) void k_mid(const float4* __restrict__ pos4,
                                                const float* __restrict__ node_sh,
                                                const int* __restrict__ start,
                                                const int* __restrict__ csr,
                                                const float* __restrict__ w1,
                                                float* __restrict__ mid) {
    __shared__ float Gl[8 * 816];
    int t = threadIdx.x;
    for (int i = t; i < 8 * 816; i += 512) Gl[i] = 0.f;
    __syncthreads();

    int nbase = blockIdx.x * 8;
    int e0 = start[nbase], e1 = start[nbase + 8];

    const float r3  = 0.57735026918962576f;
    const float r5  = 0.44721359549995794f;
    const float r6  = 0.40824829046386302f;
    const float r10 = 0.31622776601683794f;
    const float s30 = 0.18257418583505536f;
    const float rt3 = 1.7320508075688772f;
    const float c222 = 0.58554004376911990f;
    const float q6 = 0.40824829046386302f;
    const float h6 = 0.20412414523193151f;
    const float h2 = 0.35355339059327376f;
    const float r2c = 0.70710678118654752f;

    for (int idx = e0 + t; idx < e1; idx += 512) {
        int pk = csr[idx];
        int s = pk & 0xFFFF;
        int q = (pk >> 16) & 15;
        int r = (pk >> 20) & 7;
        float4 pd = pos4[nbase + r];
        float4 ps = pos4[s];
        float x = ps.x - pd.x;
        float y = ps.y - pd.y;
        float z = ps.z - pd.z;
        float B1[3], B2[5];
        sh_from_vec(x, y, z, B1, B2);
        const float4 nv0 = *(const float4*)(node_sh + s * 12);
        const float4 nv1 = *(const float4*)(node_sh + s * 12 + 4);
        float a0 = nv0.x;
        float A1[3] = {nv0.y, nv0.z, nv0.w};
        float A2[5] = {nv1.x, nv1.y, nv1.z, nv1.w, node_sh[s * 12 + 8]};
        float* gr = Gl + r * 816 + q * 51;

        atomicAdd(gr + 0, a0);
        atomicAdd(gr + 1, a0 * B1[0] * r3);
        atomicAdd(gr + 2, a0 * B1[1] * r3);
        atomicAdd(gr + 3, a0 * B1[2] * r3);
        atomicAdd(gr + 4, a0 * B2[0] * r5);
        atomicAdd(gr + 5, a0 * B2[1] * r5);
        atomicAdd(gr + 6, a0 * B2[2] * r5);
        atomicAdd(gr + 7, a0 * B2[3] * r5);
        atomicAdd(gr + 8, a0 * B2[4] * r5);
        atomicAdd(gr + 9,  A1[0] * r3);
        atomicAdd(gr + 10, A1[1] * r3);
        atomicAdd(gr + 11, A1[2] * r3);
        atomicAdd(gr + 12, -r3 * (A1[0] * B1[0] + A1[1] * B1[1] + A1[2] * B1[2]));
        atomicAdd(gr + 13, -r6 * (A1[1] * B1[2] - A1[2] * B1[1]));
        atomicAdd(gr + 14, -r6 * (A1[2] * B1[0] - A1[0] * B1[2]));
        atomicAdd(gr + 15, -r6 * (A1[0] * B1[1] - A1[1] * B1[0]));
        atomicAdd(gr + 16, r10 * (A1[0] * B1[2] + A1[2] * B1[0]));
        atomicAdd(gr + 17, r10 * (A1[0] * B1[1] + A1[1] * B1[0]));
        atomicAdd(gr + 18, s30 * (2.f * A1[1] * B1[1] - A1[0] * B1[0] - A1[2] * B1[2]));
        atomicAdd(gr + 19, r10 * (A1[1] * B1[2] + A1[2] * B1[1]));
        atomicAdd(gr + 20, r10 * (A1[2] * B1[2] - A1[0] * B1[0]));
        {
            float Byy = -B2[2] * q6 - B2[4] * r2c;
            float Bzz = 2.f * B2[2] * q6;
            float Bxx = -B2[2] * q6 + B2[4] * r2c;
            float Bxy = B2[0] * r2c;
            float Byz = B2[1] * r2c;
            float Bxz = B2[3] * r2c;
            atomicAdd(gr + 21, -r5 * (Byy * A1[0] + Byz * A1[1] + Bxy * A1[2]));
            atomicAdd(gr + 22, -r5 * (Byz * A1[0] + Bzz * A1[1] + Bxz * A1[2]));
            atomicAdd(gr + 23, -r5 * (Bxy * A1[0] + Bxz * A1[1] + Bxx * A1[2]));
        }
        atomicAdd(gr + 24, -s30 * (B2[1] * A1[0] - B2[3] * A1[2] + 2.f * B2[4] * A1[1]));
        atomicAdd(gr + 25, -s30 * (-B2[0] * A1[0] - rt3 * B2[2] * A1[2] + B2[3] * A1[1] - B2[4] * A1[2]));
        atomicAdd(gr + 26, -s30 * (rt3 * B2[1] * A1[2] - rt3 * B2[3] * A1[0]));
        atomicAdd(gr + 27, -s30 * (B2[0] * A1[2] - B2[1] * A1[1] + rt3 * B2[2] * A1[0] - B2[4] * A1[0]));
        atomicAdd(gr + 28, -s30 * (-2.f * B2[0] * A1[1] + B2[1] * A1[2] + B2[3] * A1[0]));
        atomicAdd(gr + 29, A2[0] * r5);
        atomicAdd(gr + 30, A2[1] * r5);
        atomicAdd(gr + 31, A2[2] * r5);
        atomicAdd(gr + 32, A2[3] * r5);
        atomicAdd(gr + 33, A2[4] * r5);
        {
            float Ayy = -A2[2] * q6 - A2[4] * r2c;
            float Azz = 2.f * A2[2] * q6;
            float Axx = -A2[2] * q6 + A2[4] * r2c;
            float Axy = A2[0] * r2c;
            float Ayz = A2[1] * r2c;
            float Axz = A2[3] * r2c;
            atomicAdd(gr + 34, -r5 * (Ayy * B1[0] + Ayz * B1[1] + Axy * B1[2]));
            atomicAdd(gr + 35, -r5 * (Ayz * B1[0] + Azz * B1[1] + Axz * B1[2]));
            atomicAdd(gr + 36, -r5 * (Axy * B1[0] + Axz * B1[1] + Axx * B1[2]));
        }
        atomicAdd(gr + 37, s30 * (A2[1] * B1[0] - A2[3] * B1[2] + 2.f * A2[4] * B1[1]));
        atomicAdd(gr + 38, s30 * (-A2[0] * B1[0] - rt3 * A2[2] * B1[2] + A2[3] * B1[1] - A2[4] * B1[2]));
        atomicAdd(gr + 39, s30 * (rt3 * A2[1] * B1[2] - rt3 * A2[3] * B1[0]));
        atomicAdd(gr + 40, s30 * (A2[0] * B1[2] - A2[1] * B1[1] + rt3 * A2[2] * B1[0] - A2[4] * B1[0]));
        atomicAdd(gr + 41, s30 * (-2.f * A2[0] * B1[1] + A2[1] * B1[2] + A2[3] * B1[0]));
        atomicAdd(gr + 42, r5 * (A2[0] * B2[0] + A2[1] * B2[1] + A2[2] * B2[2] +
                                 A2[3] * B2[3] + A2[4] * B2[4]));
        atomicAdd(gr + 43, s30 * (-A2[0] * B2[1] + A2[1] * B2[0] +
                                  rt3 * (A2[2] * B2[3] - A2[3] * B2[2]) +
                                  A2[3] * B2[4] - A2[4] * B2[3]));
        atomicAdd(gr + 44, s30 * (-2.f * A2[0] * B2[4] + 2.f * A2[4] * B2[0] -
                                  A2[1] * B2[3] + A2[3] * B2[1]));
        atomicAdd(gr + 45, s30 * (A2[0] * B2[3] - A2[3] * B2[0] +
                                  rt3 * (A2[1] * B2[2] - A2[2] * B2[1]) +
                                  A2[1] * B2[4] - A2[4] * B2[1]));
        atomicAdd(gr + 46, -c222 * (-q6 * (A2[0] * B2[2] + A2[2] * B2[0]) +
                                    h2 * (A2[1] * B2[3] + A2[3] * B2[1])));
        atomicAdd(gr + 47, -c222 * (h6 * (A2[1] * B2[2] + A2[2] * B2[1]) -
                                    h2 * (A2[1] * B2[4] + A2[4] * B2[1]) +
                                    h2 * (A2[0] * B2[3] + A2[3] * B2[0])));
        atomicAdd(gr + 48, -c222 * (q6 * (A2[2] * B2[2] - A2[0] * B2[0] - A2[4] * B2[4]) +
                                    h6 * (A2[1] * B2[1] + A2[3] * B2[3])));
        atomicAdd(gr + 49, -c222 * (h6 * (A2[3] * B2[2] + A2[2] * B2[3]) +
                                    h2 * (A2[3] * B2[4] + A2[4] * B2[3]) +
                                    h2 * (A2[0] * B2[1] + A2[1] * B2[0])));
        atomicAdd(gr + 50, -c222 * (-q6 * (A2[4] * B2[2] + A2[2] * B2[4]) +
                                    h2 * (A2[3] * B2[3] - A2[1] * B2[1])));
    }
    __syncthreads();

    // Phase 2: q-outer, acc[8] (static unroll), weights from global w1.
    int j = t;
    if (j >= 368) return;
    float acc[8] = {0.f, 0.f, 0.f, 0.f, 0.f, 0.f, 0.f, 0.f};
    if (j < 64) {
        int w = j;
        for (int q = 0; q < 16; q++) {
            float wa = w1[q * 64 + w];
            float wb = w1[2048 + q * 64 + w];
            float wc = w1[5248 + q * 64 + w];
            const float* Gq = Gl + q * 51;
#pragma unroll
            for (int r2 = 0; r2 < 8; r2++) {
                const float* gq = Gq + r2 * 816;
                acc[r2] += gq[0] * wa + gq[12] * wb + gq[42] * wc;
            }
        }
#pragma unroll
        for (int r2 = 0; r2 < 8; r2++)
            mid[(size_t)(nbase + r2) * 368 + j] = 0.33333333333333333f * acc[r2];
    } else if (j < 136) {
        int tt = j - 64, w = tt / 3, k = tt - 3 * w;
        for (int q = 0; q < 16; q++) {
            float wa = w1[3072 + q * 24 + w];
            float wb = w1[6272 + q * 24 + w];
            const float* Gq = Gl + q * 51;
#pragma unroll
            for (int r2 = 0; r2 < 8; r2++) {
                const float* gq = Gq + r2 * 816;
                acc[r2] += gq[13 + k] * wa + gq[43 + k] * wb;
            }
        }
#pragma unroll
        for (int r2 = 0; r2 < 8; r2++)
            mid[(size_t)(nbase + r2) * 368 + j] = 0.70710678118654752f * acc[r2];
    } else if (j < 208) {
        int tt = j - 136, w = tt / 3, k = tt - 3 * w;
        for (int q = 0; q < 16; q++) {
            float wa = w1[1024 + q * 24 + w];
            float wb = w1[1664 + q * 24 + w];
            float wc = w1[3712 + q * 24 + w];
            float wd = w1[4608 + q * 24 + w];
            const float* Gq = Gl + q * 51;
#pragma unroll
            for (int r2 = 0; r2 < 8; r2++) {
                const float* gq = Gq + r2 * 816;
                acc[r2] += gq[1 + k] * wa + gq[9 + k] * wb +
                           gq[21 + k] * wc + gq[34 + k] * wd;
            }
        }
#pragma unroll
        for (int r2 = 0; r2 < 8; r2++)
            mid[(size_t)(nbase + r2) * 368 + j] = 0.5f * acc[r2];
    } else if (j < 288) {
        int tt = j - 208, w = tt / 5, k = tt - 5 * w;
        for (int q = 0; q < 16; q++) {
            float wa = w1[1408 + q * 16 + w];
            float wb = w1[3456 + q * 16 + w];
            float wc = w1[4352 + q * 16 + w];
            float wd = w1[6656 + q * 16 + w];
            const float* Gq = Gl + q * 51;
#pragma unroll
            for (int r2 = 0; r2 < 8; r2++) {
                const float* gq = Gq + r2 * 816;
                acc[r2] += gq[4 + k] * wa + gq[16 + k] * wb +
                           gq[29 + k] * wc + gq[46 + k] * wd;
            }
        }
#pragma unroll
        for (int r2 = 0; r2 < 8; r2++)
            mid[(size_t)(nbase + r2) * 368 + j] = 0.64549722436790280f * acc[r2];
    } else {
        int tt = j - 288, w = tt / 5, k = tt - 5 * w;
        for (int q = 0; q < 16; q++) {
            float wa = w1[4096 + q * 16 + w];
            float wb = w1[4992 + q * 16 + w];
            const float* Gq = Gl + q * 51;
#pragma unroll
            for (int r2 = 0; r2 < 8; r2++) {
                const float* gq = Gq + r2 * 816;
                acc[r2] += gq[24 + k] * wa + gq[37 + k] * wb;
            }
        }
#pragma unroll
        for (int r2 = 0; r2 < 8; r2++)
            mid[(size_t)(nbase + r2) * 368 + j] = 0.91287092917527690f * acc[r2];
    }
}

// --------------- fused TP2 + graph reduce (wave per node) ------------------
// 1024 threads = 16 waves = 16 nodes/block; 2 blocks/CU -> 100% occupancy.
__global__ __launch_bounds__(1024, 8) void k_out(const float4* __restrict__ pos4,
                                                 const int* __restrict__ batch,
                                                 const int* __restrict__ start,
                                                 const int* __restrict__ csr,
                                                 const float* __restrict__ mid,
                                                 const float* __restrict__ w2,
                                                 float* __restrict__ out) {
    __shared__ float lw2[10624];
    // Permuted load: dst index -> src index in original [u][q][w] layout.
    for (int i = threadIdx.x; i < 10624; i += 1024) {
        int src;
        if (i < 4096) {                     // R0a: ((q*64+u)*4+w)
            int w = i & 3, u = (i >> 2) & 63, q = i >> 8;
            src = (u * 16 + q) * 6 + w;
        } else if (i < 6144) {              // R0b
            int t2 = i - 4096;
            int w = t2 & 1, u = (t2 >> 1) & 63, q = t2 >> 7;
            src = (u * 16 + q) * 6 + 4 + w;
        } else if (i < 6528) {              // R1: q*24+u
            int t2 = i - 6144;
            int u = t2 % 24, q = t2 / 24;
            src = 6144 + u * 16 + q;
        } else if (i < 8064) {              // R2a
            int t2 = i - 6528;
            int w = t2 & 3, a = t2 >> 2;
            int u = a % 24, q = a / 24;
            src = 6528 + (u * 16 + q) * 6 + w;
        } else if (i < 8832) {              // R2b
            int t2 = i - 8064;
            int w = t2 & 1, a = t2 >> 1;
            int u = a % 24, q = a / 24;
            src = 6528 + (u * 16 + q) * 6 + 4 + w;
        } else if (i < 9856) {              // R3a
            int t2 = i - 8832;
            int w = t2 & 3, a = t2 >> 2;
            int u = a & 15, q = a >> 4;
            src = 8832 + (u * 16 + q) * 6 + w;
        } else if (i < 10368) {             // R3b
            int t2 = i - 9856;
            int w = t2 & 1, a = t2 >> 1;
            int u = a & 15, q = a >> 4;
            src = 8832 + (u * 16 + q) * 6 + 4 + w;
        } else {                            // R4: q*16+u
            int t2 = i - 10368;
            int u = t2 & 15, q = t2 >> 4;
            src = 10368 + u * 16 + q;
        }
        lw2[i] = w2[src];
    }
    __syncthreads();

    int wave = threadIdx.x >> 6;
    int lane = threadIdx.x & 63;
    int n = blockIdx.x * 16 + wave;     // grid = 1250 -> n < 20000 always
    float4 pd = pos4[n];
    int s0 = start[n], s1 = start[n + 1];

    // per-lane unified mid-row offset for the T1/T2/T3 slot
    int offA;
    if (lane < 24)      offA = 64  + 3 * lane;            // T1, dot3
    else if (lane < 48) offA = 136 + 3 * (lane - 24);     // T2, dot3
    else                offA = 208 + 5 * (lane - 48);     // T3, dot5
    const int offB = 288 + 5 * lane;                      // T4 (lanes<16), dot5

    // per-lane u-slot partials
    float p0[6] = {0.f, 0.f, 0.f, 0.f, 0.f, 0.f};   // T0, u = lane
    float pA[6] = {0.f, 0.f, 0.f, 0.f, 0.f, 0.f};   // T1/T2/T3 by lane range
    float pB = 0.f;                                  // T4, lanes 0..15

    for (int idx = s0; idx < s1; ++idx) {
        int pk = csr[idx];
        pk = __builtin_amdgcn_readfirstlane(pk);     // wave-uniform -> scalar
        int s = pk & 0xFFFF;
        int q = (pk >> 16) & 15;
        const float* mrow = mid + (size_t)s * 368;

        // ---- issue all gathers up front ----
        float m  = mrow[lane];
        float a0 = mrow[offA], a1 = mrow[offA + 1], a2 = mrow[offA + 2];
        float a3 = 0.f, a4 = 0.f;
        if (lane >= 48) { a3 = mrow[offA + 3]; a4 = mrow[offA + 4]; }
        float b0 = 0.f, b1 = 0.f, b2 = 0.f, b3 = 0.f, b4 = 0.f;
        if (lane < 16) {
            b0 = mrow[offB];     b1 = mrow[offB + 1]; b2 = mrow[offB + 2];
            b3 = mrow[offB + 3]; b4 = mrow[offB + 4];
        }
        float4 ps = pos4[s];
        float x = ps.x - pd.x;
        float y = ps.y - pd.y;
        float z = ps.z - pd.z;

        float B1[3], B2[5];
        sh_from_vec(x, y, z, B1, B2);

        // T0: u = lane; weights 1x b128 + 1x b64, lanes contiguous
        {
            const float4 wv  = *(const float4*)(lw2 + q * 256 + lane * 4);
            const float2 wv2 = *(const float2*)(lw2 + 4096 + q * 128 + lane * 2);
            p0[0] += m * wv.x;  p0[1] += m * wv.y;
            p0[2] += m * wv.z;  p0[3] += m * wv.w;
            p0[4] += m * wv2.x; p0[5] += m * wv2.y;
        }
        // unified dd for the slot
        float dd;
        if (lane < 48) dd = a0 * B1[0] + a1 * B1[1] + a2 * B1[2];
        else           dd = a0 * B2[0] + a1 * B2[1] + a2 * B2[2] +
                            a3 * B2[3] + a4 * B2[4];
        // weight application
        if (lane < 24) {            // T1
            pA[0] += dd * lw2[6144 + q * 24 + lane];
        } else if (lane < 48) {     // T2
            int u = lane - 24;
            const float4 wv  = *(const float4*)(lw2 + 6528 + q * 96 + u * 4);
            const float2 wv2 = *(const float2*)(lw2 + 8064 + q * 48 + u * 2);
            pA[0] += dd * wv.x;  pA[1] += dd * wv.y;
            pA[2] += dd * wv.z;  pA[3] += dd * wv.w;
            pA[4] += dd * wv2.x; pA[5] += dd * wv2.y;
        } else {                    // T3
            int u = lane - 48;
            const float4 wv  = *(const float4*)(lw2 + 8832 + q * 64 + u * 4);
            const float2 wv2 = *(const float2*)(lw2 + 9856 + q * 32 + u * 2);
            pA[0] += dd * wv.x;  pA[1] += dd * wv.y;
            pA[2] += dd * wv.z;  pA[3] += dd * wv.w;
            pA[4] += dd * wv2.x; pA[5] += dd * wv2.y;
        }
        // T4: lanes 0..15
        if (lane < 16) {
            float ddB = b0 * B2[0] + b1 * B2[1] + b2 * B2[2] +
                        b3 * B2[3] + b4 * B2[4];
            pB += ddB * lw2[10368 + q * 16 + lane];
        }
    }

    const float cT0f =  0.02830690f;
    const float cT1f = -0.02635231f;
    const float cT2f = -0.01634300f;
    const float cT3f =  0.01265893f;
    const float cT4f =  0.02041241f;

    float o0 = 0.f;
    float ov[6];
#pragma unroll
    for (int w = 0; w < 6; w++) ov[w] = cT0f * p0[w];
    if (lane < 24) {
        o0 += cT1f * pA[0];
    } else if (lane < 48) {
#pragma unroll
        for (int w = 0; w < 6; w++) ov[w] += cT2f * pA[w];
    } else {
#pragma unroll
        for (int w = 0; w < 6; w++) ov[w] += cT3f * pA[w];
    }
    if (lane < 16) o0 += cT4f * pB;

#pragma unroll
    for (int off = 32; off > 0; off >>= 1) {
        o0 += __shfl_down(o0, off, 64);
#pragma unroll
        for (int w = 0; w < 6; w++) ov[w] += __shfl_down(ov[w], off, 64);
    }
    if (lane == 0) {
        float* og = out + batch[n] * 7;
        atomicAdd(og + 0, o0);
#pragma unroll
        for (int w = 0; w < 6; w++) atomicAdd(og + 1 + w, ov[w]);
    }
}

// ---------------------------------------------------------------------------
extern "C" void kernel_launch(void* const* d_in, const int* in_sizes, int n_in,
                              void* d_out, int out_size, void* d_ws, size_t ws_size,
                              hipStream_t stream) {
    const float* pos  = (const float*)d_in[0];
    const int*   z    = (const int*)d_in[1];
    const int*   bat  = (const int*)d_in[2];
    const int*   esrc = (const int*)d_in[3];
    const int*   edst = (const int*)d_in[4];
    const float* w1   = (const float*)d_in[5];
    const float* w2   = (const float*)d_in[6];
    float* out = (float*)d_out;

    int*   wsI = (int*)d_ws;
    float* wsF = (float*)d_ws;
    int* counts = wsI + 0;
    int* start  = wsI + 32768;
    int* cursor = wsI + 65536;
    int* csr    = wsI + 98304;
    float4* pos4   = (float4*)(wsF + 425984);
    float* node_sh = wsF + 524288;
    float* mid     = wsF + 1048576;

    k_zero<<<64, 256, 0, stream>>>(pos, counts, out, pos4);
    k_hist<<<(N_EDGES + 255) / 256, 256, 0, stream>>>(edst, counts);
    k_scan<<<1, 1024, 0, stream>>>(counts, start, cursor);
    k_fill<<<(N_EDGES + 255) / 256, 256, 0, stream>>>(esrc, edst, z, cursor, csr);
    k_nodesh<<<NN_NODES / 4, 256, 0, stream>>>(pos4, start, csr, node_sh);
    k_mid<<<NN_NODES / 8, 512, 0, stream>>>(pos4, node_sh, start, csr, w1, mid);
    k_out<<<NN_NODES / 16, 1024, 0, stream>>>(pos4, bat, start, csr, mid, w2, out);
}